// Round 1
// baseline (713.086 us; speedup 1.0000x reference)
//
#include <hip/hip_runtime.h>

// InferenceDynamicEmbeddingCollection: out[f, i, :] = table[values[f^4, i] % VOCAB, :]
// F=8, B*L=81920 rows per feature, DIM=128 fp32. Random-gather, memory-bound.
//
// v2: 4 rows per thread (4x memory-level parallelism on the random table
// reads), cached table loads (duplicates ~27% of rows; unique working set
// ~246 MB fits L3), nontemporal stores only (keep the write stream out of
// the caches so they hold table rows).

#define F_FEATS 8
#define BL 81920            // B*L = 4096*20
#define VOCAB 1000000u
#define DIM 128
#define NROWS (F_FEATS * BL)  // 655360
#define ROWS_PER_BLOCK 32     // 8 row-slots x 4 rows per thread
#define RPT 4                 // rows per thread

typedef float vfloat4 __attribute__((ext_vector_type(4)));

// 32 lanes per row, float4 per lane -> 512 B per row, fully coalesced.
// Block = 256 threads -> 8 row-slots -> 32 rows per block.
// BL % 32 == 0, so every block lives inside one feature: f is block-uniform.
__global__ __launch_bounds__(256) void gather_emb_kernel(
    const int* __restrict__ values,
    const float* __restrict__ table,
    float* __restrict__ out)
{
    const int lane  = threadIdx.x & 31;
    const int rslot = threadIdx.x >> 5;                 // 0..7

    const int blocksPerFeat = BL / ROWS_PER_BLOCK;      // 2560
    const int f  = blockIdx.x / blocksPerFeat;          // block-uniform
    const int sf = f ^ 4;                               // feature perm [4..7,0..3]
    const int ibase = (blockIdx.x % blocksPerFeat) * ROWS_PER_BLOCK + rslot;

    const int* __restrict__ vbase = values + (long long)sf * BL;

    // Phase 1: 4 independent id loads (all in flight together).
    int v[RPT];
#pragma unroll
    for (int k = 0; k < RPT; ++k)
        v[k] = vbase[ibase + k * 8];

    // Phase 2: slots + 4 independent 16B table loads (4x MLP on the
    // latency-critical random reads). Plain loads -> L2/L3 retention.
    const vfloat4* __restrict__ src[RPT];
#pragma unroll
    for (int k = 0; k < RPT; ++k) {
        const unsigned int slot = ((unsigned int)v[k]) % VOCAB;
        src[k] = (const vfloat4*)(table + (long long)slot * DIM);
    }

    vfloat4 d[RPT];
#pragma unroll
    for (int k = 0; k < RPT; ++k)
        d[k] = src[k][lane];

    // Phase 3: streaming nontemporal stores (output never re-read).
    const long long rbase = (long long)f * BL + ibase;
#pragma unroll
    for (int k = 0; k < RPT; ++k) {
        vfloat4* dst = (vfloat4*)(out + (rbase + (long long)k * 8) * DIM);
        __builtin_nontemporal_store(d[k], dst + lane);
    }
}

extern "C" void kernel_launch(void* const* d_in, const int* in_sizes, int n_in,
                              void* d_out, int out_size, void* d_ws, size_t ws_size,
                              hipStream_t stream)
{
    const int* values  = (const int*)d_in[0];
    const float* table = (const float*)d_in[1];
    float* out = (float*)d_out;

    const int blocks = NROWS / ROWS_PER_BLOCK;  // 20480
    gather_emb_kernel<<<dim3(blocks), dim3(256), 0, stream>>>(values, table, out);
}